// Round 5
// baseline (325.431 us; speedup 1.0000x reference)
//
#include <hip/hip_runtime.h>
#include <hip/hip_bf16.h>

typedef unsigned short ushort;
typedef unsigned int uint;
typedef unsigned long long u64;
typedef _Float16 f16;

#define NN 4096
#define PP 128
#define QQ 128
#define HD 256
#define KH 8
#define DD 64
#define KK 16384  // P*Q

typedef _Float16 f16x2 __attribute__((ext_vector_type(2)));
typedef _Float16 f16x4 __attribute__((ext_vector_type(4)));
typedef _Float16 f16x8 __attribute__((ext_vector_type(8)));
typedef __fp16 fp16x2 __attribute__((ext_vector_type(2)));  // cvt_pkrtz return type
typedef float f32x4 __attribute__((ext_vector_type(4)));

template <int N> struct IC { static constexpr int value = N; };

__device__ inline void async_lds16(const void* g, void* l) {
  __builtin_amdgcn_global_load_lds(
      (const __attribute__((address_space(1))) unsigned int*)g,
      (__attribute__((address_space(3))) unsigned int*)l, 16, 0, 0);
}

// ---------------------------------------------------------------------------
// K0: split W and Wt fp32 -> f16 hi + f16 lo; also zero the x accumulator.
// ---------------------------------------------------------------------------
__global__ __launch_bounds__(256) void k0_split2(
    const float* __restrict__ W, const float* __restrict__ Wt,
    f16* __restrict__ hiW, f16* __restrict__ loW,
    f16* __restrict__ hiT, f16* __restrict__ loT, float* __restrict__ xz) {
  const int tid = blockIdx.x * 256 + threadIdx.x;
  const int i = tid * 4;
  if (tid < (NN * HD) / 4)
    *(float4*)&xz[i] = make_float4(0.f, 0.f, 0.f, 0.f);
  const float* src;
  f16 *hi, *lo;
  int off;
  if (i < HD * PP * QQ) { src = W; hi = hiW; lo = loW; off = i; }
  else { src = Wt; hi = hiT; lo = loT; off = i - HD * PP * QQ; }
  const float4 w = *(const float4*)&src[off];
  const float wf[4] = {w.x, w.y, w.z, w.w};
  f16x4 hv, lv;
#pragma unroll
  for (int j = 0; j < 4; ++j) {
    const f16 h = (f16)wf[j];
    hv[j] = h;
    lv[j] = (f16)(wf[j] - (float)h);
  }
  *(f16x4*)&hi[off] = hv;
  *(f16x4*)&lo[off] = lv;
}

// ---------------------------------------------------------------------------
// K1 (R4 = de-risked R2): bilinear via 2-pass fp16 MFMA.
// Block 128n x 128h (4 waves of 64x64), BK=32, 32 steps ordered (quarter,p):
//  - A-fragments formed IN REGISTERS (no zhi LDS roundtrip).
//  - xn quarter (32 floats/lane) held in regs for 8 steps; SINGLE buffer:
//    reload for quarter qq+1 issued at top of step pl=7 (xqC dead there),
//    hidden under that step's 32 MFMAs.
//  - W double-buffered (2x16KB), staged at step top via global_load_lds,
//    waited at the single step-end __syncthreads.
//  - XCD-affine block decode: all 32 n-blocks of a (kb,h0) W-panel on one XCD.
// launch_bounds (256,3): ~153 VGPR fits 3 waves/EU budget -> NO forced spill
// (R2's (256,4) forced a 128-VGPR cap against ~185 live regs = heavy spill).
// LDS = 36 KB -> 3 blocks/CU at 3 waves/EU.
// ---------------------------------------------------------------------------
__global__ __launch_bounds__(256, 3) void k1_bilinear(
    const float* __restrict__ xp, const float* __restrict__ xn,
    const f16* __restrict__ Whi, const f16* __restrict__ Wlo,
    float* __restrict__ xout) {
  __shared__ f16 whi[2][128 * 32];   // [h][k], XOR-swizzled 16B segs (2x8 KB)
  __shared__ f16 wlo[2][128 * 32];   // 2x8 KB
  __shared__ float xpt[8][128];      // 4 KB

  const int t = threadIdx.x;
  // XCD-affine decode: bid%8 = XCD (round-robin dispatch); each XCD owns
  // 4 complete W panels (pan = xcd + 8*j), each panel's 32 n-blocks local.
  const int bid = blockIdx.x;
  const int xcd = bid & 7, slot = bid >> 3;
  const int jpan = slot >> 5, n_idx = slot & 31;
  const int pan = xcd + 8 * jpan;          // 0..31
  const int n0 = n_idx * 128;
  const int kb = (pan & 15) * (KK / 16);   // 1024-wide K chunk
  const int h0 = (pan >> 4) * 128;
  const int pb = kb >> 7;                  // 8 p values per block

  const int l = t & 63, w = t >> 6;
  const int wr = (w >> 1) * 64, wc = (w & 1) * 64;
  const int koff = (l >> 4) * 8;           // k-slice within 32-wide step

  int wrow[4];
#pragma unroll
  for (int i = 0; i < 4; ++i) wrow[i] = wr + i * 16 + (l & 15);

  int boff[4];
#pragma unroll
  for (int j = 0; j < 4; ++j) {
    const int hr = wc + j * 16 + (l & 15);
    boff[j] = hr * 32 + (((l >> 4) ^ ((hr ^ (hr >> 2)) & 3)) * 8);
  }

  // W staging: 128 rows x 4 segs = 512 slots; 256 thr -> 2 row-groups of 64.
  // Per-lane LDS dest = wave-uniform base + lane*16B (global_load_lds rule).
  const int shb = t >> 2, seg = t & 3;
  int gsw[2];
#pragma unroll
  for (int g = 0; g < 2; ++g) {
    const int r = shb + 64 * g;
    gsw[g] = seg ^ ((r ^ (r >> 2)) & 3);
  }

  auto stage_w = [&](int buf, int kc_) {
#pragma unroll
    for (int g = 0; g < 2; ++g) {
      const int r = shb + 64 * g;
      async_lds16(Whi + (size_t)(h0 + r) * KK + kc_ + gsw[g] * 8,
                  &whi[buf][r * 32 + seg * 8]);
      async_lds16(Wlo + (size_t)(h0 + r) * KK + kc_ + gsw[g] * 8,
                  &wlo[buf][r * 32 + seg * 8]);
    }
  };

  f32x4 xqC[4][2];  // current xn quarter (8 f32 per i-tile)
  auto load_xq = [&](int qidx) {
#pragma unroll
    for (int i = 0; i < 4; ++i) {
      const float* p = xn + (size_t)(n0 + wrow[i]) * QQ + qidx * 32 + koff;
      xqC[i][0] = *(const f32x4*)p;
      xqC[i][1] = *(const f32x4*)(p + 4);
    }
  };

  f16x8 Aa[4], Ab[4];
  auto form_A = [&](auto NPLC, f16x8 (&AN)[4]) {
    constexpr int npl = decltype(NPLC)::value;
#pragma unroll
    for (int i = 0; i < 4; ++i) {
      const float xpv = xpt[npl][wrow[i]];
      const f32x4 u0 = xqC[i][0], u1 = xqC[i][1];
      union { fp16x2 h; uint u; } c0, c1, c2, c3;
      c0.h = __builtin_amdgcn_cvt_pkrtz(xpv * u0[0], xpv * u0[1]);
      c1.h = __builtin_amdgcn_cvt_pkrtz(xpv * u0[2], xpv * u0[3]);
      c2.h = __builtin_amdgcn_cvt_pkrtz(xpv * u1[0], xpv * u1[1]);
      c3.h = __builtin_amdgcn_cvt_pkrtz(xpv * u1[2], xpv * u1[3]);
      union { uint4 u4; f16x8 f; } pk;
      pk.u4 = make_uint4(c0.u, c1.u, c2.u, c3.u);
      AN[i] = pk.f;
    }
  };

  f32x4 acc[4][4];
#pragma unroll
  for (int i = 0; i < 4; ++i)
#pragma unroll
    for (int j = 0; j < 4; ++j) acc[i][j] = (f32x4)0.f;

  // One step: [pl=7: reload xq] stage W(s+1), MFMA step s from buf[pl&1]
  // with AC, form A(s+1) from xqC.
  auto stepA = [&](auto PLC, int qq, f16x8 (&AC)[4], f16x8 (&AN)[4]) {
    constexpr int pl = decltype(PLC)::value;
    constexpr int cb = pl & 1;
    const bool notlast = (pl < 7) || (qq < 3);
    if constexpr (pl == 7) {
      // xqC is dead here (last read: pl=6's form_A). Loads for the next
      // quarter complete under this step's MFMA block.
      if (qq < 3) load_xq(qq + 1);
    }
    if (notlast) {
      constexpr int npl = (pl + 1) & 7;
      const int nqq = (pl == 7) ? qq + 1 : qq;
      stage_w((pl + 1) & 1, kb + npl * 128 + nqq * 32);
    }
#pragma unroll
    for (int j = 0; j < 4; ++j) {
      const f16x8 Bh = *(const f16x8*)&whi[cb][boff[j]];
      const f16x8 Bl = *(const f16x8*)&wlo[cb][boff[j]];
#pragma unroll
      for (int i = 0; i < 4; ++i)
        acc[i][j] = __builtin_amdgcn_mfma_f32_16x16x32_f16(AC[i], Bh, acc[i][j], 0, 0, 0);
#pragma unroll
      for (int i = 0; i < 4; ++i)
        acc[i][j] = __builtin_amdgcn_mfma_f32_16x16x32_f16(AC[i], Bl, acc[i][j], 0, 0, 0);
    }
    if (notlast) form_A(IC<(pl + 1) & 7>{}, AN);
    __syncthreads();
  };

  // ---- prologue ----
  for (int idx = t; idx < 1024; idx += 256) {
    const int p = idx & 7, n = idx >> 3;
    xpt[p][n] = xp[(size_t)(n0 + n) * PP + pb + p];
  }
  load_xq(0);
  stage_w(0, kb);          // W for step (qq=0,pl=0)
  __syncthreads();         // xpt visible + W(0) + xq0 drained
  form_A(IC<0>{}, Aa);

  // ---- main loop: 4 quarters x 8 p-steps ----
#pragma unroll 1
  for (int qq = 0; qq < 4; ++qq) {
    stepA(IC<0>{}, qq, Aa, Ab);
    stepA(IC<1>{}, qq, Ab, Aa);
    stepA(IC<2>{}, qq, Aa, Ab);
    stepA(IC<3>{}, qq, Ab, Aa);
    stepA(IC<4>{}, qq, Aa, Ab);
    stepA(IC<5>{}, qq, Ab, Aa);
    stepA(IC<6>{}, qq, Aa, Ab);
    stepA(IC<7>{}, qq, Ab, Aa);
  }

#pragma unroll
  for (int i = 0; i < 4; ++i)
#pragma unroll
    for (int j = 0; j < 4; ++j) {
      const int row = n0 + wr + i * 16 + (l >> 4) * 4;
      const int col = h0 + wc + j * 16 + (l & 15);
#pragma unroll
      for (int r = 0; r < 4; ++r)
        atomicAdd(&xout[(size_t)(row + r) * HD + col], acc[i][j][r]);
    }
}

// ---------------------------------------------------------------------------
// K23: xt[k][n][d] = sum_h (x[n][h]+b[h]) * (Wthi+Wtlo)[k*64+d][h]
// 2-pass fp16 MFMA; bias+cvt fused in A-stage; u/v dots fused in epilogue.
// ---------------------------------------------------------------------------
__global__ __launch_bounds__(256) void k23_xt(
    const float* __restrict__ x, const float* __restrict__ bb,
    const f16* __restrict__ Wthi, const f16* __restrict__ Wtlo,
    const float* __restrict__ av, float* __restrict__ xt,
    float* __restrict__ ssrc, float* __restrict__ sdst) {
  __shared__ f16 ah[64 * 40];
  __shared__ f16 bh[128 * 32];
  __shared__ f16 bl[128 * 32];
  __shared__ float red1[2][64][17];
  __shared__ float red2[2][64][17];
  const int t = threadIdx.x;
  const int n0 = blockIdx.x * 64;
  const int c0 = blockIdx.y * 128;
  const int l = t & 63, w = t >> 6;
  const int wn = (w & 1) * 32, wcc = (w >> 1) * 64;

  int aoff[2], boff[4];
#pragma unroll
  for (int i = 0; i < 2; ++i)
    aoff[i] = (wn + i * 16 + (l & 15)) * 40 + (l >> 4) * 8;
#pragma unroll
  for (int j = 0; j < 4; ++j) {
    const int hr = wcc + j * 16 + (l & 15);
    boff[j] = hr * 32 + (((l >> 4) ^ ((hr ^ (hr >> 2)) & 3)) * 8);
  }

  f32x4 acc[2][4];
#pragma unroll
  for (int i = 0; i < 2; ++i)
#pragma unroll
    for (int j = 0; j < 4; ++j) acc[i][j] = (f32x4)0.f;

  for (int kc = 0; kc < HD; kc += 32) {
    __syncthreads();
    {  // A stage: read x fp32 + bias, cvt f16, store 16B
      const int row = t >> 2, sg = t & 3;
      const float* xr = &x[(size_t)(n0 + row) * HD + kc + sg * 8];
      const float4 xa = ((const float4*)xr)[0];
      const float4 xb = ((const float4*)xr)[1];
      const float4 ba = *(const float4*)&bb[kc + sg * 8];
      const float4 bv = *(const float4*)&bb[kc + sg * 8 + 4];
      f16x8 o;
      o[0] = (f16)(xa.x + ba.x); o[1] = (f16)(xa.y + ba.y);
      o[2] = (f16)(xa.z + ba.z); o[3] = (f16)(xa.w + ba.w);
      o[4] = (f16)(xb.x + bv.x); o[5] = (f16)(xb.y + bv.y);
      o[6] = (f16)(xb.z + bv.z); o[7] = (f16)(xb.w + bv.w);
      *(f16x8*)&ah[row * 40 + sg * 8] = o;
    }
#pragma unroll
    for (int g = 0; g < 2; ++g) {  // B stage: 128 cols x 4 segs = 512 slots
      const int slot = g * 256 + t;
      const int col = slot >> 2, ps = slot & 3;
      const int ls = ps ^ ((col ^ (col >> 2)) & 3);
      *(uint4*)&bh[col * 32 + ps * 8] =
          *(const uint4*)&Wthi[(size_t)(c0 + col) * HD + kc + ls * 8];
      *(uint4*)&bl[col * 32 + ps * 8] =
          *(const uint4*)&Wtlo[(size_t)(c0 + col) * HD + kc + ls * 8];
    }
    __syncthreads();
    f16x8 Af[2];
#pragma unroll
    for (int i = 0; i < 2; ++i) Af[i] = *(const f16x8*)&ah[aoff[i]];
#pragma unroll
    for (int j = 0; j < 4; ++j) {
      const f16x8 Bh = *(const f16x8*)&bh[boff[j]];
      const f16x8 Bl = *(const f16x8*)&bl[boff[j]];
#pragma unroll
      for (int i = 0; i < 2; ++i)
        acc[i][j] = __builtin_amdgcn_mfma_f32_16x16x32_f16(Af[i], Bh, acc[i][j], 0, 0, 0);
#pragma unroll
      for (int i = 0; i < 2; ++i)
        acc[i][j] = __builtin_amdgcn_mfma_f32_16x16x32_f16(Af[i], Bl, acc[i][j], 0, 0, 0);
    }
  }

  const int hh = w >> 1;
  const int khead = (c0 >> 6) + hh;
  float a1v[4], a2v[4];
#pragma unroll
  for (int j = 0; j < 4; ++j) {
    const int d = j * 16 + (l & 15);
    a1v[j] = av[khead * (2 * DD) + d];
    a2v[j] = av[khead * (2 * DD) + DD + d];
  }

#pragma unroll
  for (int i = 0; i < 2; ++i)
#pragma unroll
    for (int r = 0; r < 4; ++r) {
      const int rowl = wn + i * 16 + (l >> 4) * 4 + r;
      float p1 = 0.f, p2 = 0.f;
#pragma unroll
      for (int j = 0; j < 4; ++j) {
        p1 += acc[i][j][r] * a1v[j];
        p2 += acc[i][j][r] * a2v[j];
      }
      red1[hh][rowl][l & 15] = p1;
      red2[hh][rowl][l & 15] = p2;
    }

#pragma unroll
  for (int i = 0; i < 2; ++i)
#pragma unroll
    for (int j = 0; j < 4; ++j) {
      const int row = n0 + wn + i * 16 + (l >> 4) * 4;
      const int colg = c0 + wcc + j * 16 + (l & 15);
      const int k = colg >> 6, d = colg & 63;
#pragma unroll
      for (int r = 0; r < 4; ++r)
        xt[((size_t)(k * NN + row + r)) * DD + d] = acc[i][j][r];
    }

  __syncthreads();
  {
    const int hh2 = t >> 7;
    const int which = (t >> 6) & 1;
    const int row = t & 63;
    const float* rp = which ? &red2[hh2][row][0] : &red1[hh2][row][0];
    float s = 0.f;
#pragma unroll
    for (int g = 0; g < 16; ++g) s += rp[g];
    const int kk = (c0 >> 6) + hh2;
    if (which) sdst[kk * NN + n0 + row] = s;
    else ssrc[kk * NN + n0 + row] = s;
  }
}

// ---------------------------------------------------------------------------
// K4a: rank-and-scatter "sort" (exact total order via packed u64 keys)
// ---------------------------------------------------------------------------
__global__ __launch_bounds__(256) void k4_rank(
    const float* __restrict__ sdst, float* __restrict__ vsorted,
    int* __restrict__ perm) {
  __shared__ u64 kv[4096];
  const int k = blockIdx.y, t = threadIdx.x;
  for (int i = t; i < 4096; i += 256) {
    const uint u = __float_as_uint(sdst[k * NN + i]);
    const uint key = (u & 0x80000000u) ? ~u : (u | 0x80000000u);
    kv[i] = ((u64)key << 32) | (uint)i;
  }
  __syncthreads();
  const int m = blockIdx.x * 256 + t;
  const u64 my = kv[m];
  int cnt = 0;
#pragma unroll 16
  for (int j = 0; j < 4096; ++j) cnt += (kv[j] < my) ? 1 : 0;
  const uint key = (uint)(my >> 32);
  const uint u = (key & 0x80000000u) ? (key ^ 0x80000000u) : ~key;
  vsorted[k * NN + cnt] = __uint_as_float(u);
  perm[k * NN + cnt] = (int)(my & 0xFFFFFFFFu);
}

// ---------------------------------------------------------------------------
// K4b: per-(head,chunk) sums; LDS-staged gather + shared exp precompute.
// ---------------------------------------------------------------------------
__global__ __launch_bounds__(64) void k4b_chunksum(
    const float* __restrict__ vs, const int* __restrict__ perm,
    const float* __restrict__ xt, float* __restrict__ Chi, float* __restrict__ Clo) {
  __shared__ float rows[64][64];
  __shared__ float eh[64], el[64];
  const int c = blockIdx.x, k = blockIdx.y, t = threadIdx.x;
  const int base = k * NN + c * 64;
  {
    const float v = vs[base + t];
    eh[t] = __expf(v);
    el[t] = __expf(0.2f * v);
  }
#pragma unroll
  for (int r = 0; r < 16; ++r) {
    const int i = r * 4 + (t >> 4);
    const int p = perm[base + i];
    *(float4*)&rows[i][(t & 15) * 4] =
        *(const float4*)&xt[((size_t)(k * NN + p)) * DD + (t & 15) * 4];
  }
  __syncthreads();
  float shi = 0.f, slo = 0.f, whs = 0.f, wls = 0.f;
#pragma unroll 8
  for (int i = 0; i < 64; ++i) {
    const float val = rows[i][t];
    shi += eh[i] * val; slo += el[i] * val;
    whs += eh[i]; wls += el[i];
  }
  const int cb = (k * 64 + c) * 65;
  Chi[cb + t] = shi;
  Clo[cb + t] = slo;
  if (t == 0) { Chi[cb + 64] = whs; Clo[cb + 64] = wls; }
}

// ---------------------------------------------------------------------------
// K4d: expand to per-position prefix/suffix arrays; chunk-scan computed
// in-block from LDS-staged chunk sums.
// ---------------------------------------------------------------------------
__global__ __launch_bounds__(64) void k4d_expand(
    const float* __restrict__ vs, const int* __restrict__ perm,
    const float* __restrict__ xt, const float* __restrict__ Chi,
    const float* __restrict__ Clo, float* __restrict__ Phi,
    float* __restrict__ Plo) {
  __shared__ float schi[64 * 65];
  __shared__ float sclo[64 * 65];
  __shared__ float rows[64][64];
  __shared__ float eh[64], el[64];
  const int c = blockIdx.x, k = blockIdx.y, t = threadIdx.x;
  const int base = k * NN + c * 64;
  for (int idx = t; idx < 4160; idx += 64) {
    schi[idx] = Chi[k * 4160 + idx];
    sclo[idx] = Clo[k * 4160 + idx];
  }
  {
    const float v = vs[base + t];
    eh[t] = __expf(v);
    el[t] = __expf(0.2f * v);
  }
#pragma unroll
  for (int r = 0; r < 16; ++r) {
    const int i = r * 4 + (t >> 4);
    const int p = perm[base + i];
    *(float4*)&rows[i][(t & 15) * 4] =
        *(const float4*)&xt[((size_t)(k * NN + p)) * DD + (t & 15) * 4];
  }
  __syncthreads();

  float run = 0.f, wrun = 0.f;
  for (int cc = 0; cc < c; ++cc) {
    run += sclo[cc * 65 + t];
    wrun += sclo[cc * 65 + 64];
  }
  float runS = 0.f, wrunS = 0.f;
  for (int cc = c + 1; cc < 64; ++cc) {
    runS += schi[cc * 65 + t];
    wrunS += schi[cc * 65 + 64];
  }

  for (int i = 0; i < 64; ++i) {
    const size_t rb = ((size_t)(k * 4097) + c * 64 + i) * 65;
    Plo[rb + t] = run;
    if (t == 0) Plo[rb + 64] = wrun;
    run += el[i] * rows[i][t];
    wrun += el[i];
  }
  if (c == 63) {
    const size_t rb = ((size_t)(k * 4097) + 4096) * 65;
    Plo[rb + t] = run;
    if (t == 0) Plo[rb + 64] = wrun;
  }
  for (int i = 63; i >= 0; --i) {
    runS += eh[i] * rows[i][t];
    wrunS += eh[i];
    const size_t rb = ((size_t)(k * 4097) + c * 64 + i) * 65;
    Phi[rb + t] = runS;
    if (t == 0) Phi[rb + 64] = wrunS;
  }
  if (c == 63) {
    const size_t rb = ((size_t)(k * 4097) + 4096) * 65;
    Phi[rb + t] = 0.f;
    if (t == 0) Phi[rb + 64] = 0.f;
  }
}

// ---------------------------------------------------------------------------
// K6: per query: LDS binary search + combine + tanh. 16 queries/block
// (amortizes the vsh staging 4x vs the 4-query version).
// ---------------------------------------------------------------------------
__global__ __launch_bounds__(256) void k6_final(
    const float* __restrict__ ssrc, const float* __restrict__ vsorted,
    const float* __restrict__ Phi, const float* __restrict__ Plo,
    float* __restrict__ out) {
  __shared__ float vsh[4096];
  __shared__ int posSh[16];
  const int t = threadIdx.x;
  const int q0 = blockIdx.x * 16;
  const int k = q0 >> 12;
  for (int idx = t; idx < 1024; idx += 256)
    *(float4*)&vsh[idx * 4] = *(const float4*)&vsorted[k * NN + idx * 4];
  __syncthreads();
  if (t < 16) {
    const float thr = -ssrc[q0 + t];
    int lo = 0, hi = 4096;
    while (lo < hi) {
      const int mid = (lo + hi) >> 1;
      if (vsh[mid] < thr) lo = mid + 1; else hi = mid;
    }
    posSh[t] = lo;
  }
  __syncthreads();
  const int d = t & 63;
#pragma unroll
  for (int qq = 0; qq < 4; ++qq) {
    const int ql = qq * 4 + (t >> 6);
    const int qi = q0 + ql;
    const int n = qi & 4095;
    const float u = ssrc[qi];
    const size_t rb = ((size_t)(k * 4097) + posSh[ql]) * 65;
    const float eu = __expf(u), el = __expf(0.2f * u);
    const float num = eu * Phi[rb + d] + el * Plo[rb + d];
    const float den = eu * Phi[rb + 64] + el * Plo[rb + 64];
    out[(size_t)n * (KH * DD) + k * DD + d] = tanhf(num / den);
  }
}

extern "C" void kernel_launch(void* const* d_in, const int* in_sizes, int n_in,
                              void* d_out, int out_size, void* d_ws, size_t ws_size,
                              hipStream_t stream) {
  const float* xp = (const float*)d_in[0];
  const float* xn = (const float*)d_in[1];
  const float* W = (const float*)d_in[2];
  const float* bb = (const float*)d_in[3];
  const float* Wt = (const float*)d_in[4];
  const float* av = (const float*)d_in[5];
  float* out = (float*)d_out;

  char* ws = (char*)d_ws;
  // Phi/Plo overlay the W splits (temporally disjoint).
  f16* Whi    = (f16*)(ws);                       // 8 MB
  f16* Wlo    = (f16*)(ws + 8388608);             // 8 MB
  float* Phi  = (float*)(ws);                     // 8.52 MB (overlay)
  float* Plo  = (float*)(ws + 8522240);           // 8.52 MB (overlay)
  float* x    = (float*)(ws + 17044480);          // 4 MB
  float* xt   = (float*)(ws + 21238784);          // 8 MB
  f16* Wthi   = (f16*)(ws + 31724544);            // 256 KB
  f16* Wtlo   = (f16*)(ws + 31986688);            // 256 KB
  float* ssrc = (float*)(ws + 32248832);          // 128 KB
  float* sdst = (float*)(ws + 32379904);          // 128 KB
  float* vsort= (float*)(ws + 32510976);          // 128 KB
  int*   perm = (int*)  (ws + 32642048);          // 128 KB
  float* Chi  = (float*)(ws + 32773120);          // 133 KB
  float* Clo  = (float*)(ws + 32906240);          // 133 KB -> ends ~33.0 MB

  k0_split2<<<(HD * PP * QQ + KH * DD * HD) / 1024, 256, 0, stream>>>(
      W, Wt, Whi, Wlo, Wthi, Wtlo, x);
  k1_bilinear<<<1024, 256, 0, stream>>>(xp, xn, Whi, Wlo, x);
  k23_xt<<<dim3(NN / 64, 4), 256, 0, stream>>>(x, bb, Wthi, Wtlo, av, xt, ssrc, sdst);
  k4_rank<<<dim3(16, KH), 256, 0, stream>>>(sdst, vsort, perm);
  k4b_chunksum<<<dim3(64, KH), 64, 0, stream>>>(vsort, perm, xt, Chi, Clo);
  k4d_expand<<<dim3(64, KH), 64, 0, stream>>>(vsort, perm, xt, Chi, Clo, Phi, Plo);
  k6_final<<<(KH * NN) / 16, 256, 0, stream>>>(ssrc, vsort, Phi, Plo, out);
}

// Round 6
// 253.217 us; speedup vs baseline: 1.2852x; 1.2852x over previous
//
#include <hip/hip_runtime.h>
#include <hip/hip_bf16.h>

typedef unsigned short ushort;
typedef unsigned int uint;
typedef unsigned long long u64;
typedef _Float16 f16;

#define NN 4096
#define PP 128
#define QQ 128
#define HD 256
#define KH 8
#define DD 64
#define KK 16384  // P*Q

typedef _Float16 f16x2 __attribute__((ext_vector_type(2)));
typedef _Float16 f16x4 __attribute__((ext_vector_type(4)));
typedef _Float16 f16x8 __attribute__((ext_vector_type(8)));
typedef __fp16 fp16x2 __attribute__((ext_vector_type(2)));  // cvt_pkrtz return type
typedef float f32x4 __attribute__((ext_vector_type(4)));

__device__ inline void async_lds16(const void* g, void* l) {
  __builtin_amdgcn_global_load_lds(
      (const __attribute__((address_space(1))) unsigned int*)g,
      (__attribute__((address_space(3))) unsigned int*)l, 16, 0, 0);
}

// ---------------------------------------------------------------------------
// K0: split W and Wt fp32 -> f16 hi + f16 lo; also zero the x accumulator.
// ---------------------------------------------------------------------------
__global__ __launch_bounds__(256) void k0_split2(
    const float* __restrict__ W, const float* __restrict__ Wt,
    f16* __restrict__ hiW, f16* __restrict__ loW,
    f16* __restrict__ hiT, f16* __restrict__ loT, float* __restrict__ xz) {
  const int tid = blockIdx.x * 256 + threadIdx.x;
  const int i = tid * 4;
  if (tid < (NN * HD) / 4)
    *(float4*)&xz[i] = make_float4(0.f, 0.f, 0.f, 0.f);
  const float* src;
  f16 *hi, *lo;
  int off;
  if (i < HD * PP * QQ) { src = W; hi = hiW; lo = loW; off = i; }
  else { src = Wt; hi = hiT; lo = loT; off = i - HD * PP * QQ; }
  const float4 w = *(const float4*)&src[off];
  const float wf[4] = {w.x, w.y, w.z, w.w};
  f16x4 hv, lv;
#pragma unroll
  for (int j = 0; j < 4; ++j) {
    const f16 h = (f16)wf[j];
    hv[j] = h;
    lv[j] = (f16)(wf[j] - (float)h);
  }
  *(f16x4*)&hi[off] = hv;
  *(f16x4*)&lo[off] = lv;
}

// ---------------------------------------------------------------------------
// K1: bilinear via 2-pass fp16 MFMA — verified baseline structure (118 µs).
// R5 change is ONLY the block-index decode: XCD-panel-affine mapping so all
// 32 n-blocks of a (kb,h0) W-panel (512 KB x2) land on one XCD's L2.
// Inner loop, LDS layout, barriers, epilogue: byte-identical to baseline.
// LDS = 30 KB -> 4 blocks/CU; grid flat 1024.
// ---------------------------------------------------------------------------
__global__ __launch_bounds__(256, 4) void k1_bilinear(
    const float* __restrict__ xp, const float* __restrict__ xn,
    const f16* __restrict__ Whi, const f16* __restrict__ Wlo,
    float* __restrict__ xout) {
  __shared__ f16 whi[128 * 32];   // [h][k], XOR-swizzled 16B segs (8 KB)
  __shared__ f16 wlo[128 * 32];   // 8 KB
  __shared__ f16 zhi[128 * 40];   // [n][k] padded 32->40 (10 KB)
  __shared__ float xpt[8][128];   // 4 KB

  const int t = threadIdx.x;
  // XCD-panel-affine decode (bijective over 1024): bid%8 = XCD under
  // round-robin dispatch; each XCD owns panels pan = xcd + 8*jpan.
  const int bid = blockIdx.x;
  const int xcd = bid & 7, slot = bid >> 3;
  const int jpan = slot >> 5, n_idx = slot & 31;
  const int pan = xcd + 8 * jpan;          // 0..31
  const int n0 = n_idx * 128;
  const int kb = (pan & 15) * (KK / 16);   // 1024-wide K chunk
  const int h0 = (pan >> 4) * 128;
  const int pb = kb >> 7;                  // 8 p values per block

  for (int idx = t; idx < 1024; idx += 256) {
    const int p = idx & 7, n = idx >> 3;
    xpt[p][n] = xp[(size_t)(n0 + n) * PP + pb + p];
  }

  const int l = t & 63, w = t >> 6;
  const int wr = (w >> 1) * 64, wc = (w & 1) * 64;

  int aoff[4], boff[4];
#pragma unroll
  for (int i = 0; i < 4; ++i)
    aoff[i] = (wr + i * 16 + (l & 15)) * 40 + (l >> 4) * 8;
#pragma unroll
  for (int j = 0; j < 4; ++j) {
    const int hr = wc + j * 16 + (l & 15);
    boff[j] = hr * 32 + (((l >> 4) ^ ((hr ^ (hr >> 2)) & 3)) * 8);
  }

  // W staging: 128 rows x 4 segs = 512 slots; 256 thr -> 2 row-groups of 64
  const int shb = t >> 2, seg = t & 3;
  int gsw[2];
#pragma unroll
  for (int g = 0; g < 2; ++g) {
    const int r = shb + 64 * g;
    gsw[g] = seg ^ ((r ^ (r >> 2)) & 3);
  }

  const int zn = t >> 1, zko = (t & 1) * 16;

  f32x4 acc[4][4];
#pragma unroll
  for (int i = 0; i < 4; ++i)
#pragma unroll
    for (int j = 0; j < 4; ++j) acc[i][j] = (f32x4)0.f;

  for (int c = 0; c < 32; ++c) {
    const int kc = kb + c * 32;
    const int pl = c >> 2;             // local p index (0..7)
    const int q0 = (c & 3) * 32;       // q base within row

    __syncthreads();  // previous step's fragment reads done (covers xpt too)

#pragma unroll
    for (int g = 0; g < 2; ++g) {
      const int r = shb + 64 * g;
      async_lds16(Whi + (size_t)(h0 + r) * KK + kc + gsw[g] * 8,
                  whi + r * 32 + seg * 8);
      async_lds16(Wlo + (size_t)(h0 + r) * KK + kc + gsw[g] * 8,
                  wlo + r * 32 + seg * 8);
    }

    // form Z tile: 128 rows x 32 k; 16 elems/thread, fp16 round via pkrtz
    {
      const float xpv = xpt[pl][zn];
      const float* xr = xn + (size_t)(n0 + zn) * QQ + q0 + zko;
      const float4 v0 = ((const float4*)xr)[0];
      const float4 v1 = ((const float4*)xr)[1];
      const float4 v2 = ((const float4*)xr)[2];
      const float4 v3 = ((const float4*)xr)[3];
      float zz[16] = {v0.x, v0.y, v0.z, v0.w, v1.x, v1.y, v1.z, v1.w,
                      v2.x, v2.y, v2.z, v2.w, v3.x, v3.y, v3.z, v3.w};
      union { uint u[8]; uint4 q[2]; } ph;
#pragma unroll
      for (int j = 0; j < 8; ++j) {
        union { fp16x2 h; uint u; } cv;
        cv.h = __builtin_amdgcn_cvt_pkrtz(xpv * zz[2 * j], xpv * zz[2 * j + 1]);
        ph.u[j] = cv.u;
      }
      const int zo = zn * 40 + zko;
      *(uint4*)&zhi[zo] = ph.q[0];
      *(uint4*)&zhi[zo + 8] = ph.q[1];
    }

    __syncthreads();  // W (vmcnt drained) + Z visible

    f16x8 Ah[4];
#pragma unroll
    for (int i = 0; i < 4; ++i) Ah[i] = *(const f16x8*)&zhi[aoff[i]];
#pragma unroll
    for (int j = 0; j < 4; ++j) {
      const f16x8 Bh = *(const f16x8*)&whi[boff[j]];
      const f16x8 Bl = *(const f16x8*)&wlo[boff[j]];
#pragma unroll
      for (int i = 0; i < 4; ++i)
        acc[i][j] = __builtin_amdgcn_mfma_f32_16x16x32_f16(Ah[i], Bh, acc[i][j], 0, 0, 0);
#pragma unroll
      for (int i = 0; i < 4; ++i)
        acc[i][j] = __builtin_amdgcn_mfma_f32_16x16x32_f16(Ah[i], Bl, acc[i][j], 0, 0, 0);
    }
  }

#pragma unroll
  for (int i = 0; i < 4; ++i)
#pragma unroll
    for (int j = 0; j < 4; ++j) {
      const int row = n0 + wr + i * 16 + (l >> 4) * 4;
      const int col = h0 + wc + j * 16 + (l & 15);
#pragma unroll
      for (int r = 0; r < 4; ++r)
        atomicAdd(&xout[(size_t)(row + r) * HD + col], acc[i][j][r]);
    }
}

// ---------------------------------------------------------------------------
// K23: xt[k][n][d] = sum_h (x[n][h]+b[h]) * (Wthi+Wtlo)[k*64+d][h]
// 2-pass fp16 MFMA; bias+cvt fused in A-stage; u/v dots fused in epilogue.
// ---------------------------------------------------------------------------
__global__ __launch_bounds__(256) void k23_xt(
    const float* __restrict__ x, const float* __restrict__ bb,
    const f16* __restrict__ Wthi, const f16* __restrict__ Wtlo,
    const float* __restrict__ av, float* __restrict__ xt,
    float* __restrict__ ssrc, float* __restrict__ sdst) {
  __shared__ f16 ah[64 * 40];
  __shared__ f16 bh[128 * 32];
  __shared__ f16 bl[128 * 32];
  __shared__ float red1[2][64][17];
  __shared__ float red2[2][64][17];
  const int t = threadIdx.x;
  const int n0 = blockIdx.x * 64;
  const int c0 = blockIdx.y * 128;
  const int l = t & 63, w = t >> 6;
  const int wn = (w & 1) * 32, wcc = (w >> 1) * 64;

  int aoff[2], boff[4];
#pragma unroll
  for (int i = 0; i < 2; ++i)
    aoff[i] = (wn + i * 16 + (l & 15)) * 40 + (l >> 4) * 8;
#pragma unroll
  for (int j = 0; j < 4; ++j) {
    const int hr = wcc + j * 16 + (l & 15);
    boff[j] = hr * 32 + (((l >> 4) ^ ((hr ^ (hr >> 2)) & 3)) * 8);
  }

  f32x4 acc[2][4];
#pragma unroll
  for (int i = 0; i < 2; ++i)
#pragma unroll
    for (int j = 0; j < 4; ++j) acc[i][j] = (f32x4)0.f;

  for (int kc = 0; kc < HD; kc += 32) {
    __syncthreads();
    {  // A stage: read x fp32 + bias, cvt f16, store 16B
      const int row = t >> 2, sg = t & 3;
      const float* xr = &x[(size_t)(n0 + row) * HD + kc + sg * 8];
      const float4 xa = ((const float4*)xr)[0];
      const float4 xb = ((const float4*)xr)[1];
      const float4 ba = *(const float4*)&bb[kc + sg * 8];
      const float4 bv = *(const float4*)&bb[kc + sg * 8 + 4];
      f16x8 o;
      o[0] = (f16)(xa.x + ba.x); o[1] = (f16)(xa.y + ba.y);
      o[2] = (f16)(xa.z + ba.z); o[3] = (f16)(xa.w + ba.w);
      o[4] = (f16)(xb.x + bv.x); o[5] = (f16)(xb.y + bv.y);
      o[6] = (f16)(xb.z + bv.z); o[7] = (f16)(xb.w + bv.w);
      *(f16x8*)&ah[row * 40 + sg * 8] = o;
    }
#pragma unroll
    for (int g = 0; g < 2; ++g) {  // B stage: 128 cols x 4 segs = 512 slots
      const int slot = g * 256 + t;
      const int col = slot >> 2, ps = slot & 3;
      const int ls = ps ^ ((col ^ (col >> 2)) & 3);
      *(uint4*)&bh[col * 32 + ps * 8] =
          *(const uint4*)&Wthi[(size_t)(c0 + col) * HD + kc + ls * 8];
      *(uint4*)&bl[col * 32 + ps * 8] =
          *(const uint4*)&Wtlo[(size_t)(c0 + col) * HD + kc + ls * 8];
    }
    __syncthreads();
    f16x8 Af[2];
#pragma unroll
    for (int i = 0; i < 2; ++i) Af[i] = *(const f16x8*)&ah[aoff[i]];
#pragma unroll
    for (int j = 0; j < 4; ++j) {
      const f16x8 Bh = *(const f16x8*)&bh[boff[j]];
      const f16x8 Bl = *(const f16x8*)&bl[boff[j]];
#pragma unroll
      for (int i = 0; i < 2; ++i)
        acc[i][j] = __builtin_amdgcn_mfma_f32_16x16x32_f16(Af[i], Bh, acc[i][j], 0, 0, 0);
#pragma unroll
      for (int i = 0; i < 2; ++i)
        acc[i][j] = __builtin_amdgcn_mfma_f32_16x16x32_f16(Af[i], Bl, acc[i][j], 0, 0, 0);
    }
  }

  const int hh = w >> 1;
  const int khead = (c0 >> 6) + hh;
  float a1v[4], a2v[4];
#pragma unroll
  for (int j = 0; j < 4; ++j) {
    const int d = j * 16 + (l & 15);
    a1v[j] = av[khead * (2 * DD) + d];
    a2v[j] = av[khead * (2 * DD) + DD + d];
  }

#pragma unroll
  for (int i = 0; i < 2; ++i)
#pragma unroll
    for (int r = 0; r < 4; ++r) {
      const int rowl = wn + i * 16 + (l >> 4) * 4 + r;
      float p1 = 0.f, p2 = 0.f;
#pragma unroll
      for (int j = 0; j < 4; ++j) {
        p1 += acc[i][j][r] * a1v[j];
        p2 += acc[i][j][r] * a2v[j];
      }
      red1[hh][rowl][l & 15] = p1;
      red2[hh][rowl][l & 15] = p2;
    }

#pragma unroll
  for (int i = 0; i < 2; ++i)
#pragma unroll
    for (int j = 0; j < 4; ++j) {
      const int row = n0 + wn + i * 16 + (l >> 4) * 4;
      const int colg = c0 + wcc + j * 16 + (l & 15);
      const int k = colg >> 6, d = colg & 63;
#pragma unroll
      for (int r = 0; r < 4; ++r)
        xt[((size_t)(k * NN + row + r)) * DD + d] = acc[i][j][r];
    }

  __syncthreads();
  {
    const int hh2 = t >> 7;
    const int which = (t >> 6) & 1;
    const int row = t & 63;
    const float* rp = which ? &red2[hh2][row][0] : &red1[hh2][row][0];
    float s = 0.f;
#pragma unroll
    for (int g = 0; g < 16; ++g) s += rp[g];
    const int kk = (c0 >> 6) + hh2;
    if (which) sdst[kk * NN + n0 + row] = s;
    else ssrc[kk * NN + n0 + row] = s;
  }
}

// ---------------------------------------------------------------------------
// K4a: rank-and-scatter "sort" (exact total order via packed u64 keys).
// R5: grid 128 -> 256 blocks (all CUs busy) and the per-m scan split in two:
// thread pair (idx, idx+128) each counts a 2048-wide j-half; ushort partials
// combined in LDS. Same keys, same strict order -> bit-identical output.
// ---------------------------------------------------------------------------
__global__ __launch_bounds__(256) void k4_rank(
    const float* __restrict__ sdst, float* __restrict__ vsorted,
    int* __restrict__ perm) {
  __shared__ u64 kv[4096];
  __shared__ ushort pcnt[256];
  const int k = blockIdx.y, t = threadIdx.x;
  for (int i = t; i < 4096; i += 256) {
    const uint u = __float_as_uint(sdst[k * NN + i]);
    const uint key = (u & 0x80000000u) ? ~u : (u | 0x80000000u);
    kv[i] = ((u64)key << 32) | (uint)i;
  }
  __syncthreads();
  const int idx = t & 127;          // local m index (0..127)
  const int half = t >> 7;          // j-half this thread scans
  const u64 my = kv[blockIdx.x * 128 + idx];
  const int j0 = half * 2048;
  int cnt = 0;
#pragma unroll 16
  for (int j = 0; j < 2048; ++j) cnt += (kv[j0 + j] < my) ? 1 : 0;
  pcnt[t] = (ushort)cnt;
  __syncthreads();
  if (t < 128) {
    const int tot = (int)pcnt[t] + (int)pcnt[t + 128];
    const u64 my2 = kv[blockIdx.x * 128 + t];
    const uint key = (uint)(my2 >> 32);
    const uint u = (key & 0x80000000u) ? (key ^ 0x80000000u) : ~key;
    vsorted[k * NN + tot] = __uint_as_float(u);
    perm[k * NN + tot] = (int)(my2 & 0xFFFFFFFFu);
  }
}

// ---------------------------------------------------------------------------
// K4b: per-(head,chunk) sums; LDS-staged gather + shared exp precompute.
// ---------------------------------------------------------------------------
__global__ __launch_bounds__(64) void k4b_chunksum(
    const float* __restrict__ vs, const int* __restrict__ perm,
    const float* __restrict__ xt, float* __restrict__ Chi, float* __restrict__ Clo) {
  __shared__ float rows[64][64];
  __shared__ float eh[64], el[64];
  const int c = blockIdx.x, k = blockIdx.y, t = threadIdx.x;
  const int base = k * NN + c * 64;
  {
    const float v = vs[base + t];
    eh[t] = __expf(v);
    el[t] = __expf(0.2f * v);
  }
#pragma unroll
  for (int r = 0; r < 16; ++r) {
    const int i = r * 4 + (t >> 4);
    const int p = perm[base + i];
    *(float4*)&rows[i][(t & 15) * 4] =
        *(const float4*)&xt[((size_t)(k * NN + p)) * DD + (t & 15) * 4];
  }
  __syncthreads();
  float shi = 0.f, slo = 0.f, whs = 0.f, wls = 0.f;
#pragma unroll 8
  for (int i = 0; i < 64; ++i) {
    const float val = rows[i][t];
    shi += eh[i] * val; slo += el[i] * val;
    whs += eh[i]; wls += el[i];
  }
  const int cb = (k * 64 + c) * 65;
  Chi[cb + t] = shi;
  Clo[cb + t] = slo;
  if (t == 0) { Chi[cb + 64] = whs; Clo[cb + 64] = wls; }
}

// ---------------------------------------------------------------------------
// K4d: expand to per-position prefix/suffix arrays; chunk-scan computed
// in-block from LDS-staged chunk sums.
// ---------------------------------------------------------------------------
__global__ __launch_bounds__(64) void k4d_expand(
    const float* __restrict__ vs, const int* __restrict__ perm,
    const float* __restrict__ xt, const float* __restrict__ Chi,
    const float* __restrict__ Clo, float* __restrict__ Phi,
    float* __restrict__ Plo) {
  __shared__ float schi[64 * 65];
  __shared__ float sclo[64 * 65];
  __shared__ float rows[64][64];
  __shared__ float eh[64], el[64];
  const int c = blockIdx.x, k = blockIdx.y, t = threadIdx.x;
  const int base = k * NN + c * 64;
  for (int idx = t; idx < 4160; idx += 64) {
    schi[idx] = Chi[k * 4160 + idx];
    sclo[idx] = Clo[k * 4160 + idx];
  }
  {
    const float v = vs[base + t];
    eh[t] = __expf(v);
    el[t] = __expf(0.2f * v);
  }
#pragma unroll
  for (int r = 0; r < 16; ++r) {
    const int i = r * 4 + (t >> 4);
    const int p = perm[base + i];
    *(float4*)&rows[i][(t & 15) * 4] =
        *(const float4*)&xt[((size_t)(k * NN + p)) * DD + (t & 15) * 4];
  }
  __syncthreads();

  float run = 0.f, wrun = 0.f;
  for (int cc = 0; cc < c; ++cc) {
    run += sclo[cc * 65 + t];
    wrun += sclo[cc * 65 + 64];
  }
  float runS = 0.f, wrunS = 0.f;
  for (int cc = c + 1; cc < 64; ++cc) {
    runS += schi[cc * 65 + t];
    wrunS += schi[cc * 65 + 64];
  }

  for (int i = 0; i < 64; ++i) {
    const size_t rb = ((size_t)(k * 4097) + c * 64 + i) * 65;
    Plo[rb + t] = run;
    if (t == 0) Plo[rb + 64] = wrun;
    run += el[i] * rows[i][t];
    wrun += el[i];
  }
  if (c == 63) {
    const size_t rb = ((size_t)(k * 4097) + 4096) * 65;
    Plo[rb + t] = run;
    if (t == 0) Plo[rb + 64] = wrun;
  }
  for (int i = 63; i >= 0; --i) {
    runS += eh[i] * rows[i][t];
    wrunS += eh[i];
    const size_t rb = ((size_t)(k * 4097) + c * 64 + i) * 65;
    Phi[rb + t] = runS;
    if (t == 0) Phi[rb + 64] = wrunS;
  }
  if (c == 63) {
    const size_t rb = ((size_t)(k * 4097) + 4096) * 65;
    Phi[rb + t] = 0.f;
    if (t == 0) Phi[rb + 64] = 0.f;
  }
}

// ---------------------------------------------------------------------------
// K6: per query: LDS binary search + combine + tanh. 16 queries/block
// (amortizes the vsh staging 4x vs the 4-query version).
// ---------------------------------------------------------------------------
__global__ __launch_bounds__(256) void k6_final(
    const float* __restrict__ ssrc, const float* __restrict__ vsorted,
    const float* __restrict__ Phi, const float* __restrict__ Plo,
    float* __restrict__ out) {
  __shared__ float vsh[4096];
  __shared__ int posSh[16];
  const int t = threadIdx.x;
  const int q0 = blockIdx.x * 16;
  const int k = q0 >> 12;
  for (int idx = t; idx < 1024; idx += 256)
    *(float4*)&vsh[idx * 4] = *(const float4*)&vsorted[k * NN + idx * 4];
  __syncthreads();
  if (t < 16) {
    const float thr = -ssrc[q0 + t];
    int lo = 0, hi = 4096;
    while (lo < hi) {
      const int mid = (lo + hi) >> 1;
      if (vsh[mid] < thr) lo = mid + 1; else hi = mid;
    }
    posSh[t] = lo;
  }
  __syncthreads();
  const int d = t & 63;
#pragma unroll
  for (int qq = 0; qq < 4; ++qq) {
    const int ql = qq * 4 + (t >> 6);
    const int qi = q0 + ql;
    const int n = qi & 4095;
    const float u = ssrc[qi];
    const size_t rb = ((size_t)(k * 4097) + posSh[ql]) * 65;
    const float eu = __expf(u), el = __expf(0.2f * u);
    const float num = eu * Phi[rb + d] + el * Plo[rb + d];
    const float den = eu * Phi[rb + 64] + el * Plo[rb + 64];
    out[(size_t)n * (KH * DD) + k * DD + d] = tanhf(num / den);
  }
}

extern "C" void kernel_launch(void* const* d_in, const int* in_sizes, int n_in,
                              void* d_out, int out_size, void* d_ws, size_t ws_size,
                              hipStream_t stream) {
  const float* xp = (const float*)d_in[0];
  const float* xn = (const float*)d_in[1];
  const float* W = (const float*)d_in[2];
  const float* bb = (const float*)d_in[3];
  const float* Wt = (const float*)d_in[4];
  const float* av = (const float*)d_in[5];
  float* out = (float*)d_out;

  char* ws = (char*)d_ws;
  // Phi/Plo overlay the W splits (temporally disjoint).
  f16* Whi    = (f16*)(ws);                       // 8 MB
  f16* Wlo    = (f16*)(ws + 8388608);             // 8 MB
  float* Phi  = (float*)(ws);                     // 8.52 MB (overlay)
  float* Plo  = (float*)(ws + 8522240);           // 8.52 MB (overlay)
  float* x    = (float*)(ws + 17044480);          // 4 MB
  float* xt   = (float*)(ws + 21238784);          // 8 MB
  f16* Wthi   = (f16*)(ws + 31724544);            // 256 KB
  f16* Wtlo   = (f16*)(ws + 31986688);            // 256 KB
  float* ssrc = (float*)(ws + 32248832);          // 128 KB
  float* sdst = (float*)(ws + 32379904);          // 128 KB
  float* vsort= (float*)(ws + 32510976);          // 128 KB
  int*   perm = (int*)  (ws + 32642048);          // 128 KB
  float* Chi  = (float*)(ws + 32773120);          // 133 KB
  float* Clo  = (float*)(ws + 32906240);          // 133 KB -> ends ~33.0 MB

  k0_split2<<<(HD * PP * QQ + KH * DD * HD) / 1024, 256, 0, stream>>>(
      W, Wt, Whi, Wlo, Wthi, Wtlo, x);
  k1_bilinear<<<1024, 256, 0, stream>>>(xp, xn, Whi, Wlo, x);
  k23_xt<<<dim3(NN / 64, 4), 256, 0, stream>>>(x, bb, Wthi, Wtlo, av, xt, ssrc, sdst);
  k4_rank<<<dim3(32, KH), 256, 0, stream>>>(sdst, vsort, perm);
  k4b_chunksum<<<dim3(64, KH), 64, 0, stream>>>(vsort, perm, xt, Chi, Clo);
  k4d_expand<<<dim3(64, KH), 64, 0, stream>>>(vsort, perm, xt, Chi, Clo, Phi, Plo);
  k6_final<<<(KH * NN) / 16, 256, 0, stream>>>(ssrc, vsort, Phi, Plo, out);
}

// Round 7
// 246.698 us; speedup vs baseline: 1.3191x; 1.0264x over previous
//
#include <hip/hip_runtime.h>
#include <hip/hip_bf16.h>

typedef unsigned short ushort;
typedef unsigned int uint;
typedef unsigned long long u64;
typedef _Float16 f16;

#define NN 4096
#define PP 128
#define QQ 128
#define HD 256
#define KH 8
#define DD 64
#define KK 16384  // P*Q

typedef _Float16 f16x2 __attribute__((ext_vector_type(2)));
typedef _Float16 f16x4 __attribute__((ext_vector_type(4)));
typedef _Float16 f16x8 __attribute__((ext_vector_type(8)));
typedef __fp16 fp16x2 __attribute__((ext_vector_type(2)));  // cvt_pkrtz return type
typedef float f32x4 __attribute__((ext_vector_type(4)));

__device__ inline void async_lds16(const void* g, void* l) {
  __builtin_amdgcn_global_load_lds(
      (const __attribute__((address_space(1))) unsigned int*)g,
      (__attribute__((address_space(3))) unsigned int*)l, 16, 0, 0);
}

// ---------------------------------------------------------------------------
// K0: split W and Wt fp32 -> f16 hi + f16 lo; also zero the x accumulator.
// ---------------------------------------------------------------------------
__global__ __launch_bounds__(256) void k0_split2(
    const float* __restrict__ W, const float* __restrict__ Wt,
    f16* __restrict__ hiW, f16* __restrict__ loW,
    f16* __restrict__ hiT, f16* __restrict__ loT, float* __restrict__ xz) {
  const int tid = blockIdx.x * 256 + threadIdx.x;
  const int i = tid * 4;
  if (tid < (NN * HD) / 4)
    *(float4*)&xz[i] = make_float4(0.f, 0.f, 0.f, 0.f);
  const float* src;
  f16 *hi, *lo;
  int off;
  if (i < HD * PP * QQ) { src = W; hi = hiW; lo = loW; off = i; }
  else { src = Wt; hi = hiT; lo = loT; off = i - HD * PP * QQ; }
  const float4 w = *(const float4*)&src[off];
  const float wf[4] = {w.x, w.y, w.z, w.w};
  f16x4 hv, lv;
#pragma unroll
  for (int j = 0; j < 4; ++j) {
    const f16 h = (f16)wf[j];
    hv[j] = h;
    lv[j] = (f16)(wf[j] - (float)h);
  }
  *(f16x4*)&hi[off] = hv;
  *(f16x4*)&lo[off] = lv;
}

// ---------------------------------------------------------------------------
// K1: bilinear via 2-pass fp16 MFMA. Baseline structure + R5 XCD swizzle.
// R6: (a) zhi stride 40 -> 32 halves with the same 16B-granule XOR swizzle
//     as whi (A-reads/z-writes were 4-way bank-conflicted at pad-40;
//     SQ_LDS_BANK_CONFLICT 8.6M ~= 12% of k1 cycles);
//     (b) xn prefetch: next step's 4xfloat4 loaded into regs during the
//     MFMA phase (xn is read-only; removes ~300-400cyc exposed L2 latency
//     per step). +16 VGPR on a 56-VGPR kernel.
// LDS = 28 KB; grid flat 1024, XCD-panel-affine decode.
// ---------------------------------------------------------------------------
__global__ __launch_bounds__(256, 4) void k1_bilinear(
    const float* __restrict__ xp, const float* __restrict__ xn,
    const f16* __restrict__ Whi, const f16* __restrict__ Wlo,
    float* __restrict__ xout) {
  __shared__ f16 whi[128 * 32];   // [h][k], XOR-swizzled 16B segs (8 KB)
  __shared__ f16 wlo[128 * 32];   // 8 KB
  __shared__ f16 zhi[128 * 32];   // [n][k], XOR-swizzled 16B segs (8 KB)
  __shared__ float xpt[8][128];   // 4 KB

  const int t = threadIdx.x;
  // XCD-panel-affine decode (bijective over 1024): bid%8 = XCD under
  // round-robin dispatch; each XCD owns panels pan = xcd + 8*jpan.
  const int bid = blockIdx.x;
  const int xcd = bid & 7, slot = bid >> 3;
  const int jpan = slot >> 5, n_idx = slot & 31;
  const int pan = xcd + 8 * jpan;          // 0..31
  const int n0 = n_idx * 128;
  const int kb = (pan & 15) * (KK / 16);   // 1024-wide K chunk
  const int h0 = (pan >> 4) * 128;
  const int pb = kb >> 7;                  // 8 p values per block

  for (int idx = t; idx < 1024; idx += 256) {
    const int p = idx & 7, n = idx >> 3;
    xpt[p][n] = xp[(size_t)(n0 + n) * PP + pb + p];
  }

  const int l = t & 63, w = t >> 6;
  const int wr = (w >> 1) * 64, wc = (w & 1) * 64;

  int aoff[4], boff[4];
#pragma unroll
  for (int i = 0; i < 4; ++i) {
    const int row = wr + i * 16 + (l & 15);
    aoff[i] = row * 32 + (((l >> 4) ^ ((row ^ (row >> 2)) & 3)) * 8);
  }
#pragma unroll
  for (int j = 0; j < 4; ++j) {
    const int hr = wc + j * 16 + (l & 15);
    boff[j] = hr * 32 + (((l >> 4) ^ ((hr ^ (hr >> 2)) & 3)) * 8);
  }

  // W staging: 128 rows x 4 segs = 512 slots; 256 thr -> 2 row-groups of 64
  const int shb = t >> 2, seg = t & 3;
  int gsw[2];
#pragma unroll
  for (int g = 0; g < 2; ++g) {
    const int r = shb + 64 * g;
    gsw[g] = seg ^ ((r ^ (r >> 2)) & 3);
  }

  const int zn = t >> 1, zko = (t & 1) * 16;
  // z-write swizzle: thread covers logical segs zs0, zs0+1 of row zn.
  const int zm = (zn ^ (zn >> 2)) & 3;
  const int zs0 = (t & 1) * 2;
  const int zo0 = zn * 32 + ((zs0 ^ zm) * 8);
  const int zo1 = zn * 32 + (((zs0 + 1) ^ zm) * 8);

  f32x4 acc[4][4];
#pragma unroll
  for (int i = 0; i < 4; ++i)
#pragma unroll
    for (int j = 0; j < 4; ++j) acc[i][j] = (f32x4)0.f;

  // Prefetch xn window for step 0 (q0 = 0).
  const float* xr0 = xn + (size_t)(n0 + zn) * QQ + zko;
  float4 xv0 = ((const float4*)xr0)[0];
  float4 xv1 = ((const float4*)xr0)[1];
  float4 xv2 = ((const float4*)xr0)[2];
  float4 xv3 = ((const float4*)xr0)[3];

  for (int c = 0; c < 32; ++c) {
    const int kc = kb + c * 32;
    const int pl = c >> 2;             // local p index (0..7)

    __syncthreads();  // A: previous step's fragment reads done

#pragma unroll
    for (int g = 0; g < 2; ++g) {
      const int r = shb + 64 * g;
      async_lds16(Whi + (size_t)(h0 + r) * KK + kc + gsw[g] * 8,
                  whi + r * 32 + seg * 8);
      async_lds16(Wlo + (size_t)(h0 + r) * KK + kc + gsw[g] * 8,
                  wlo + r * 32 + seg * 8);
    }

    // form Z tile from prefetched regs: 16 elems/thread, pkrtz round
    {
      const float xpv = xpt[pl][zn];
      float zz[16] = {xv0.x, xv0.y, xv0.z, xv0.w, xv1.x, xv1.y, xv1.z, xv1.w,
                      xv2.x, xv2.y, xv2.z, xv2.w, xv3.x, xv3.y, xv3.z, xv3.w};
      union { uint u[8]; uint4 q[2]; } ph;
#pragma unroll
      for (int j = 0; j < 8; ++j) {
        union { fp16x2 h; uint u; } cv;
        cv.h = __builtin_amdgcn_cvt_pkrtz(xpv * zz[2 * j], xpv * zz[2 * j + 1]);
        ph.u[j] = cv.u;
      }
      *(uint4*)&zhi[zo0] = ph.q[0];
      *(uint4*)&zhi[zo1] = ph.q[1];
    }

    __syncthreads();  // B: W (vmcnt drained) + Z visible

    // Prefetch xn for step c+1 (consumed after next barrier A; latency
    // hidden under this step's MFMA phase).
    if (c < 31) {
      const int q0n = ((c + 1) & 3) * 32;
      const float* xr = xn + (size_t)(n0 + zn) * QQ + q0n + zko;
      xv0 = ((const float4*)xr)[0];
      xv1 = ((const float4*)xr)[1];
      xv2 = ((const float4*)xr)[2];
      xv3 = ((const float4*)xr)[3];
    }

    f16x8 Ah[4];
#pragma unroll
    for (int i = 0; i < 4; ++i) Ah[i] = *(const f16x8*)&zhi[aoff[i]];
#pragma unroll
    for (int j = 0; j < 4; ++j) {
      const f16x8 Bh = *(const f16x8*)&whi[boff[j]];
      const f16x8 Bl = *(const f16x8*)&wlo[boff[j]];
#pragma unroll
      for (int i = 0; i < 4; ++i)
        acc[i][j] = __builtin_amdgcn_mfma_f32_16x16x32_f16(Ah[i], Bh, acc[i][j], 0, 0, 0);
#pragma unroll
      for (int i = 0; i < 4; ++i)
        acc[i][j] = __builtin_amdgcn_mfma_f32_16x16x32_f16(Ah[i], Bl, acc[i][j], 0, 0, 0);
    }
  }

#pragma unroll
  for (int i = 0; i < 4; ++i)
#pragma unroll
    for (int j = 0; j < 4; ++j) {
      const int row = n0 + wr + i * 16 + (l >> 4) * 4;
      const int col = h0 + wc + j * 16 + (l & 15);
#pragma unroll
      for (int r = 0; r < 4; ++r)
        atomicAdd(&xout[(size_t)(row + r) * HD + col], acc[i][j][r]);
    }
}

// ---------------------------------------------------------------------------
// K23: xt[k][n][d] = sum_h (x[n][h]+b[h]) * (Wthi+Wtlo)[k*64+d][h]
// 2-pass fp16 MFMA; bias+cvt fused in A-stage; u/v dots fused in epilogue.
// R6: ah stride 40 -> 32 halves + XOR swizzle (same fix as k1's zhi).
// ---------------------------------------------------------------------------
__global__ __launch_bounds__(256) void k23_xt(
    const float* __restrict__ x, const float* __restrict__ bb,
    const f16* __restrict__ Wthi, const f16* __restrict__ Wtlo,
    const float* __restrict__ av, float* __restrict__ xt,
    float* __restrict__ ssrc, float* __restrict__ sdst) {
  __shared__ f16 ah[64 * 32];
  __shared__ f16 bh[128 * 32];
  __shared__ f16 bl[128 * 32];
  __shared__ float red1[2][64][17];
  __shared__ float red2[2][64][17];
  const int t = threadIdx.x;
  const int n0 = blockIdx.x * 64;
  const int c0 = blockIdx.y * 128;
  const int l = t & 63, w = t >> 6;
  const int wn = (w & 1) * 32, wcc = (w >> 1) * 64;

  int aoff[2], boff[4];
#pragma unroll
  for (int i = 0; i < 2; ++i) {
    const int row = wn + i * 16 + (l & 15);
    aoff[i] = row * 32 + (((l >> 4) ^ ((row ^ (row >> 2)) & 3)) * 8);
  }
#pragma unroll
  for (int j = 0; j < 4; ++j) {
    const int hr = wcc + j * 16 + (l & 15);
    boff[j] = hr * 32 + (((l >> 4) ^ ((hr ^ (hr >> 2)) & 3)) * 8);
  }

  f32x4 acc[2][4];
#pragma unroll
  for (int i = 0; i < 2; ++i)
#pragma unroll
    for (int j = 0; j < 4; ++j) acc[i][j] = (f32x4)0.f;

  for (int kc = 0; kc < HD; kc += 32) {
    __syncthreads();
    {  // A stage: read x fp32 + bias, cvt f16, store 16B (swizzled seg)
      const int row = t >> 2, sg = t & 3;
      const float* xr = &x[(size_t)(n0 + row) * HD + kc + sg * 8];
      const float4 xa = ((const float4*)xr)[0];
      const float4 xb = ((const float4*)xr)[1];
      const float4 ba = *(const float4*)&bb[kc + sg * 8];
      const float4 bv = *(const float4*)&bb[kc + sg * 8 + 4];
      f16x8 o;
      o[0] = (f16)(xa.x + ba.x); o[1] = (f16)(xa.y + ba.y);
      o[2] = (f16)(xa.z + ba.z); o[3] = (f16)(xa.w + ba.w);
      o[4] = (f16)(xb.x + bv.x); o[5] = (f16)(xb.y + bv.y);
      o[6] = (f16)(xb.z + bv.z); o[7] = (f16)(xb.w + bv.w);
      const int sgs = sg ^ ((row ^ (row >> 2)) & 3);
      *(f16x8*)&ah[row * 32 + sgs * 8] = o;
    }
#pragma unroll
    for (int g = 0; g < 2; ++g) {  // B stage: 128 cols x 4 segs = 512 slots
      const int slot = g * 256 + t;
      const int col = slot >> 2, ps = slot & 3;
      const int ls = ps ^ ((col ^ (col >> 2)) & 3);
      *(uint4*)&bh[col * 32 + ps * 8] =
          *(const uint4*)&Wthi[(size_t)(c0 + col) * HD + kc + ls * 8];
      *(uint4*)&bl[col * 32 + ps * 8] =
          *(const uint4*)&Wtlo[(size_t)(c0 + col) * HD + kc + ls * 8];
    }
    __syncthreads();
    f16x8 Af[2];
#pragma unroll
    for (int i = 0; i < 2; ++i) Af[i] = *(const f16x8*)&ah[aoff[i]];
#pragma unroll
    for (int j = 0; j < 4; ++j) {
      const f16x8 Bh = *(const f16x8*)&bh[boff[j]];
      const f16x8 Bl = *(const f16x8*)&bl[boff[j]];
#pragma unroll
      for (int i = 0; i < 2; ++i)
        acc[i][j] = __builtin_amdgcn_mfma_f32_16x16x32_f16(Af[i], Bh, acc[i][j], 0, 0, 0);
#pragma unroll
      for (int i = 0; i < 2; ++i)
        acc[i][j] = __builtin_amdgcn_mfma_f32_16x16x32_f16(Af[i], Bl, acc[i][j], 0, 0, 0);
    }
  }

  const int hh = w >> 1;
  const int khead = (c0 >> 6) + hh;
  float a1v[4], a2v[4];
#pragma unroll
  for (int j = 0; j < 4; ++j) {
    const int d = j * 16 + (l & 15);
    a1v[j] = av[khead * (2 * DD) + d];
    a2v[j] = av[khead * (2 * DD) + DD + d];
  }

#pragma unroll
  for (int i = 0; i < 2; ++i)
#pragma unroll
    for (int r = 0; r < 4; ++r) {
      const int rowl = wn + i * 16 + (l >> 4) * 4 + r;
      float p1 = 0.f, p2 = 0.f;
#pragma unroll
      for (int j = 0; j < 4; ++j) {
        p1 += acc[i][j][r] * a1v[j];
        p2 += acc[i][j][r] * a2v[j];
      }
      red1[hh][rowl][l & 15] = p1;
      red2[hh][rowl][l & 15] = p2;
    }

#pragma unroll
  for (int i = 0; i < 2; ++i)
#pragma unroll
    for (int j = 0; j < 4; ++j) {
      const int row = n0 + wn + i * 16 + (l >> 4) * 4;
      const int colg = c0 + wcc + j * 16 + (l & 15);
      const int k = colg >> 6, d = colg & 63;
#pragma unroll
      for (int r = 0; r < 4; ++r)
        xt[((size_t)(k * NN + row + r)) * DD + d] = acc[i][j][r];
    }

  __syncthreads();
  {
    const int hh2 = t >> 7;
    const int which = (t >> 6) & 1;
    const int row = t & 63;
    const float* rp = which ? &red2[hh2][row][0] : &red1[hh2][row][0];
    float s = 0.f;
#pragma unroll
    for (int g = 0; g < 16; ++g) s += rp[g];
    const int kk = (c0 >> 6) + hh2;
    if (which) sdst[kk * NN + n0 + row] = s;
    else ssrc[kk * NN + n0 + row] = s;
  }
}

// ---------------------------------------------------------------------------
// K4a: rank-and-scatter "sort" (exact total order via packed u64 keys).
// 256 blocks; thread pair (idx, idx+128) each counts a 2048-wide j-half.
// ---------------------------------------------------------------------------
__global__ __launch_bounds__(256) void k4_rank(
    const float* __restrict__ sdst, float* __restrict__ vsorted,
    int* __restrict__ perm) {
  __shared__ u64 kv[4096];
  __shared__ ushort pcnt[256];
  const int k = blockIdx.y, t = threadIdx.x;
  for (int i = t; i < 4096; i += 256) {
    const uint u = __float_as_uint(sdst[k * NN + i]);
    const uint key = (u & 0x80000000u) ? ~u : (u | 0x80000000u);
    kv[i] = ((u64)key << 32) | (uint)i;
  }
  __syncthreads();
  const int idx = t & 127;          // local m index (0..127)
  const int half = t >> 7;          // j-half this thread scans
  const u64 my = kv[blockIdx.x * 128 + idx];
  const int j0 = half * 2048;
  int cnt = 0;
#pragma unroll 16
  for (int j = 0; j < 2048; ++j) cnt += (kv[j0 + j] < my) ? 1 : 0;
  pcnt[t] = (ushort)cnt;
  __syncthreads();
  if (t < 128) {
    const int tot = (int)pcnt[t] + (int)pcnt[t + 128];
    const u64 my2 = kv[blockIdx.x * 128 + t];
    const uint key = (uint)(my2 >> 32);
    const uint u = (key & 0x80000000u) ? (key ^ 0x80000000u) : ~key;
    vsorted[k * NN + tot] = __uint_as_float(u);
    perm[k * NN + tot] = (int)(my2 & 0xFFFFFFFFu);
  }
}

// ---------------------------------------------------------------------------
// K4b: per-(head,chunk) sums; LDS-staged gather + shared exp precompute.
// ---------------------------------------------------------------------------
__global__ __launch_bounds__(64) void k4b_chunksum(
    const float* __restrict__ vs, const int* __restrict__ perm,
    const float* __restrict__ xt, float* __restrict__ Chi, float* __restrict__ Clo) {
  __shared__ float rows[64][64];
  __shared__ float eh[64], el[64];
  const int c = blockIdx.x, k = blockIdx.y, t = threadIdx.x;
  const int base = k * NN + c * 64;
  {
    const float v = vs[base + t];
    eh[t] = __expf(v);
    el[t] = __expf(0.2f * v);
  }
#pragma unroll
  for (int r = 0; r < 16; ++r) {
    const int i = r * 4 + (t >> 4);
    const int p = perm[base + i];
    *(float4*)&rows[i][(t & 15) * 4] =
        *(const float4*)&xt[((size_t)(k * NN + p)) * DD + (t & 15) * 4];
  }
  __syncthreads();
  float shi = 0.f, slo = 0.f, whs = 0.f, wls = 0.f;
#pragma unroll 8
  for (int i = 0; i < 64; ++i) {
    const float val = rows[i][t];
    shi += eh[i] * val; slo += el[i] * val;
    whs += eh[i]; wls += el[i];
  }
  const int cb = (k * 64 + c) * 65;
  Chi[cb + t] = shi;
  Clo[cb + t] = slo;
  if (t == 0) { Chi[cb + 64] = whs; Clo[cb + 64] = wls; }
}

// ---------------------------------------------------------------------------
// K4d: expand to per-position prefix/suffix arrays.
// R6: split into independent prefix (z=0, Plo/el) and suffix (z=1, Phi/eh)
// passes -> 2x wave count for this latency-bound gather (was 2 waves/CU),
// LDS ~50KB -> ~33KB. Identical arithmetic and order per output.
// ---------------------------------------------------------------------------
__global__ __launch_bounds__(64) void k4d_expand(
    const float* __restrict__ vs, const int* __restrict__ perm,
    const float* __restrict__ xt, const float* __restrict__ Chi,
    const float* __restrict__ Clo, float* __restrict__ Phi,
    float* __restrict__ Plo) {
  __shared__ float scs[64 * 65];
  __shared__ float rows[64][64];
  __shared__ float ev[64];
  const int c = blockIdx.x, k = blockIdx.y, t = threadIdx.x;
  const int pass = blockIdx.z;  // 0 = prefix/Plo, 1 = suffix/Phi
  const int base = k * NN + c * 64;
  const float* Cs = pass ? Chi : Clo;
  for (int idx = t; idx < 4160; idx += 64) scs[idx] = Cs[k * 4160 + idx];
  {
    const float v = vs[base + t];
    ev[t] = pass ? __expf(v) : __expf(0.2f * v);
  }
#pragma unroll
  for (int r = 0; r < 16; ++r) {
    const int i = r * 4 + (t >> 4);
    const int p = perm[base + i];
    *(float4*)&rows[i][(t & 15) * 4] =
        *(const float4*)&xt[((size_t)(k * NN + p)) * DD + (t & 15) * 4];
  }
  __syncthreads();

  if (pass == 0) {
    float run = 0.f, wrun = 0.f;
    for (int cc = 0; cc < c; ++cc) {
      run += scs[cc * 65 + t];
      wrun += scs[cc * 65 + 64];
    }
    for (int i = 0; i < 64; ++i) {
      const size_t rb = ((size_t)(k * 4097) + c * 64 + i) * 65;
      Plo[rb + t] = run;
      if (t == 0) Plo[rb + 64] = wrun;
      run += ev[i] * rows[i][t];
      wrun += ev[i];
    }
    if (c == 63) {
      const size_t rb = ((size_t)(k * 4097) + 4096) * 65;
      Plo[rb + t] = run;
      if (t == 0) Plo[rb + 64] = wrun;
    }
  } else {
    float runS = 0.f, wrunS = 0.f;
    for (int cc = c + 1; cc < 64; ++cc) {
      runS += scs[cc * 65 + t];
      wrunS += scs[cc * 65 + 64];
    }
    for (int i = 63; i >= 0; --i) {
      runS += ev[i] * rows[i][t];
      wrunS += ev[i];
      const size_t rb = ((size_t)(k * 4097) + c * 64 + i) * 65;
      Phi[rb + t] = runS;
      if (t == 0) Phi[rb + 64] = wrunS;
    }
    if (c == 63) {
      const size_t rb = ((size_t)(k * 4097) + 4096) * 65;
      Phi[rb + t] = 0.f;
      if (t == 0) Phi[rb + 64] = 0.f;
    }
  }
}

// ---------------------------------------------------------------------------
// K6: per query: LDS binary search + combine + tanh. 16 queries/block
// (amortizes the vsh staging 4x vs the 4-query version).
// ---------------------------------------------------------------------------
__global__ __launch_bounds__(256) void k6_final(
    const float* __restrict__ ssrc, const float* __restrict__ vsorted,
    const float* __restrict__ Phi, const float* __restrict__ Plo,
    float* __restrict__ out) {
  __shared__ float vsh[4096];
  __shared__ int posSh[16];
  const int t = threadIdx.x;
  const int q0 = blockIdx.x * 16;
  const int k = q0 >> 12;
  for (int idx = t; idx < 1024; idx += 256)
    *(float4*)&vsh[idx * 4] = *(const float4*)&vsorted[k * NN + idx * 4];
  __syncthreads();
  if (t < 16) {
    const float thr = -ssrc[q0 + t];
    int lo = 0, hi = 4096;
    while (lo < hi) {
      const int mid = (lo + hi) >> 1;
      if (vsh[mid] < thr) lo = mid + 1; else hi = mid;
    }
    posSh[t] = lo;
  }
  __syncthreads();
  const int d = t & 63;
#pragma unroll
  for (int qq = 0; qq < 4; ++qq) {
    const int ql = qq * 4 + (t >> 6);
    const int qi = q0 + ql;
    const int n = qi & 4095;
    const float u = ssrc[qi];
    const size_t rb = ((size_t)(k * 4097) + posSh[ql]) * 65;
    const float eu = __expf(u), el = __expf(0.2f * u);
    const float num = eu * Phi[rb + d] + el * Plo[rb + d];
    const float den = eu * Phi[rb + 64] + el * Plo[rb + 64];
    out[(size_t)n * (KH * DD) + k * DD + d] = tanhf(num / den);
  }
}

extern "C" void kernel_launch(void* const* d_in, const int* in_sizes, int n_in,
                              void* d_out, int out_size, void* d_ws, size_t ws_size,
                              hipStream_t stream) {
  const float* xp = (const float*)d_in[0];
  const float* xn = (const float*)d_in[1];
  const float* W = (const float*)d_in[2];
  const float* bb = (const float*)d_in[3];
  const float* Wt = (const float*)d_in[4];
  const float* av = (const float*)d_in[5];
  float* out = (float*)d_out;

  char* ws = (char*)d_ws;
  // Phi/Plo overlay the W splits (temporally disjoint).
  f16* Whi    = (f16*)(ws);                       // 8 MB
  f16* Wlo    = (f16*)(ws + 8388608);             // 8 MB
  float* Phi  = (float*)(ws);                     // 8.52 MB (overlay)
  float* Plo  = (float*)(ws + 8522240);           // 8.52 MB (overlay)
  float* x    = (float*)(ws + 17044480);          // 4 MB
  float* xt   = (float*)(ws + 21238784);          // 8 MB
  f16* Wthi   = (f16*)(ws + 31724544);            // 256 KB
  f16* Wtlo   = (f16*)(ws + 31986688);            // 256 KB
  float* ssrc = (float*)(ws + 32248832);          // 128 KB
  float* sdst = (float*)(ws + 32379904);          // 128 KB
  float* vsort= (float*)(ws + 32510976);          // 128 KB
  int*   perm = (int*)  (ws + 32642048);          // 128 KB
  float* Chi  = (float*)(ws + 32773120);          // 133 KB
  float* Clo  = (float*)(ws + 32906240);          // 133 KB -> ends ~33.0 MB

  k0_split2<<<(HD * PP * QQ + KH * DD * HD) / 1024, 256, 0, stream>>>(
      W, Wt, Whi, Wlo, Wthi, Wtlo, x);
  k1_bilinear<<<1024, 256, 0, stream>>>(xp, xn, Whi, Wlo, x);
  k23_xt<<<dim3(NN / 64, 4), 256, 0, stream>>>(x, bb, Wthi, Wtlo, av, xt, ssrc, sdst);
  k4_rank<<<dim3(32, KH), 256, 0, stream>>>(sdst, vsort, perm);
  k4b_chunksum<<<dim3(64, KH), 64, 0, stream>>>(vsort, perm, xt, Chi, Clo);
  k4d_expand<<<dim3(64, KH, 2), 64, 0, stream>>>(vsort, perm, xt, Chi, Clo, Phi, Plo);
  k6_final<<<(KH * NN) / 16, 256, 0, stream>>>(ssrc, vsort, Phi, Plo, out);
}